// Round 1
// 72.084 us; speedup vs baseline: 1.0081x; 1.0081x over previous
//
#include <hip/hip_runtime.h>
#include <math.h>

// S4D kernel materialization:
//   out[d,l] = dt_d * sum_n Re{ (Cr + i Ci) * B * exp(dt_d * (Ar + i Ai) * l) }
// D=1024, N=64, L=1024, fp32.
//
// R3 design (vs R2 @ 72.4us total, kernel ~32us):
//  - Kernel is latency-bound (~15% of issue roofline at 16 waves/CU).
//    512-thread blocks + __launch_bounds__(512,8) -> 4 blocks/CU x 8 waves
//    = 32 waves/CU (2x latency hiding). Grid stays 1024 (one block per d),
//    all blocks co-resident.
//  - whT[n][k] = (C*B*dt) * exp(dtA*16k): the output weight is folded into
//    the hi table at build time, so the main loop is y0 = whT*loT (4 ops)
//    instead of w*(hi*lo) (8 ops).
//  - ws[n] = {Re r, Im r, 2*Re r, -|r|^2} precomputed (r = exp(dtA*128)):
//    recurrence coefficients read as one broadcast b128, not recomputed
//    per thread (-3 VALU/n).
//  - Main loop: 26 VALU + 3 LDS per (n, 8 l's) vs R2's ~33.
//  - Writeback parallelized across all 512 threads (4-way LDS reduce).

#define D_MODEL 1024
#define N_STATE 64
#define SEQ_LEN 1024
#define CHUNK   8
#define TPD     128                 // threads covering t (l = t + 128*j)
#define NSPLIT  4
#define NPT     (N_STATE / NSPLIT)  // 16 n's per thread
#define BLOCK   (TPD * NSPLIT)      // 512

#define INV_2PI 0.15915494309189535

__device__ __forceinline__ float sin_rev(float f) { return __builtin_amdgcn_sinf(f); }
__device__ __forceinline__ float cos_rev(float f) { return __builtin_amdgcn_cosf(f); }

__global__ __launch_bounds__(BLOCK, 8) void s4d_kernel(
    const float* __restrict__ A_real, const float* __restrict__ A_imag,
    const float* __restrict__ C, const float* __restrict__ log_dt,
    const float* __restrict__ B, float* __restrict__ out)
{
  __shared__ float2 whT[N_STATE][8];           // w * exp(dtA*16k)      4 KB
  __shared__ float2 loT[N_STATE][16];          // exp(dtA*m)            8 KB
  __shared__ float4 ws[N_STATE];               // {str,sti,2str,-|r|^2} 1 KB
  __shared__ float  red[NSPLIT][CHUNK][TPD];   // n-split reduction    16 KB

  const int tid = threadIdx.x;
  const int d   = blockIdx.x;
  const float dt = __expf(log_dt[d]);

  // ---- build tables: 64n x 24 entries = 1536, 3 per thread ----
  #pragma unroll
  for (int i = 0; i < 3; ++i) {
    const int e   = tid + BLOCK * i;          // < 1536
    const int n   = e / 24;
    const int idx = e - n * 24;
    const int steps = (idx < 8) ? (idx << 4) : (idx - 8);
    const float ar = A_real[d * N_STATE + n];
    const float ai = A_imag[d * N_STATE + n];
    const float xr = dt * ar;
    const double drev = (double)dt * (double)ai * INV_2PI;  // rev per unit l
    const double ph = drev * (double)steps;
    const float  fr = (float)(ph - floor(ph));
    const float mag = __expf(xr * (float)steps);
    const float vr = mag * cos_rev(fr);
    const float vi = mag * sin_rev(fr);
    if (idx < 8) {
      const float b  = B[d * N_STATE + n];
      const float cr = C[(d * N_STATE + n) * 2 + 0] * b * dt;
      const float ci = C[(d * N_STATE + n) * 2 + 1] * b * dt;
      whT[n][idx] = make_float2(fmaf(cr, vr, -(ci * vi)),
                                fmaf(cr, vi,   ci * vr));
    } else {
      loT[n][idx - 8] = make_float2(vr, vi);
    }
  }
  if (tid < N_STATE) {
    const int n = tid;
    const float ar = A_real[d * N_STATE + n];
    const float ai = A_imag[d * N_STATE + n];
    const float xr = dt * ar;
    const double drev = (double)dt * (double)ai * INV_2PI;
    const double ph = drev * 128.0;
    const float  fr = (float)(ph - floor(ph));
    const float mag = __expf(xr * 128.0f);
    const float str = mag * cos_rev(fr);
    const float sti = mag * sin_rev(fr);
    ws[n] = make_float4(str, sti, str + str, -fmaf(str, str, sti * sti));
  }
  __syncthreads();

  const int t     = tid & (TPD - 1);
  const int split = tid >> 7;          // 0..3
  const int thi   = t >> 4;
  const int tlo   = t & 15;

  float acc[CHUNK];
  #pragma unroll
  for (int j = 0; j < CHUNK; ++j) acc[j] = 0.0f;

  const int n0 = split * NPT;
  #pragma unroll 2
  for (int nn = 0; nn < NPT; ++nn) {
    const int n = n0 + nn;
    const float4 w4 = ws[n];           // str, sti, a2, nb (broadcast)
    const float2 wh = whT[n][thi];
    const float2 lo = loT[n][tlo];
    // y0 = w * state(t) = whT * loT
    float u0       = fmaf(wh.x, lo.x, -(wh.y * lo.y));
    const float yi = fmaf(wh.x, lo.y,   wh.y * lo.x);
    // u1 = Re(y0 * r)
    float u1 = fmaf(u0, w4.x, -(yi * w4.y));
    acc[0] += u0;
    acc[1] += u1;
    #pragma unroll
    for (int j = 2; j < CHUNK; ++j) {
      const float u2 = fmaf(w4.z, u1, w4.w * u0);   // 2Re(r)*u1 - |r|^2*u0
      acc[j] += u2;
      u0 = u1; u1 = u2;
    }
  }

  // ---- 4-way n-split reduction, writeback over all 512 threads ----
  #pragma unroll
  for (int j = 0; j < CHUNK; ++j) red[split][j][t] = acc[j];
  __syncthreads();

  #pragma unroll
  for (int i = 0; i < 2; ++i) {
    const int e  = tid + BLOCK * i;    // < 1024
    const int j  = e >> 7;
    const int tt = e & 127;
    out[d * SEQ_LEN + j * TPD + tt] =
        red[0][j][tt] + red[1][j][tt] + red[2][j][tt] + red[3][j][tt];
  }
}

extern "C" void kernel_launch(void* const* d_in, const int* in_sizes, int n_in,
                              void* d_out, int out_size, void* d_ws, size_t ws_size,
                              hipStream_t stream) {
  const float* A_real = (const float*)d_in[0];
  const float* A_imag = (const float*)d_in[1];
  const float* C      = (const float*)d_in[2];
  const float* log_dt = (const float*)d_in[3];
  const float* B      = (const float*)d_in[4];
  float* out = (float*)d_out;

  s4d_kernel<<<dim3(D_MODEL), dim3(BLOCK), 0, stream>>>(
      A_real, A_imag, C, log_dt, B, out);
}